// Round 8
// baseline (74.059 us; speedup 1.0000x reference)
//
#include <hip/hip_runtime.h>
#include <math.h>

#define N_ 2048
#define K_ 512
#define J_ 256

typedef float f32x4 __attribute__((ext_vector_type(4)));
typedef __attribute__((address_space(3))) float       lds_f;
typedef const __attribute__((address_space(1))) float glb_f;

// 2 muls + 1 max3 + 1 min3 per 2 products = 2.0 VALU ops/product.
#define MAX3(acc, a, b) asm("v_max3_f32 %0, %0, %1, %2" : "+v"(acc) : "v"(a), "v"(b))
#define MIN3(acc, a, b) asm("v_min3_f32 %0, %0, %1, %2" : "+v"(acc) : "v"(a), "v"(b))

// Grid 512 x 512 thr (8 waves), 1 block/CU (128 KB LDS), 2 waves/SIMD.
// Block = 32n x 32j x FULL K=512; wave kq owns k-chunk [kq*64,+64).
// Lane grid 8x8 (rn,cj); per-lane tile 4n x 4j (rows rn+8i, cols cj+8jj):
// per 4-k quad: 8 ds_read_b128 feed 128 VALU insts -> LDS/VALU ratio 0.75-1.125
// (vs R7's 2.25: (4,2) tile was LDS-pipe-bound at 15.4us of b128 traffic).
// XOR swizzle: [row][k] stored at slot (k>>2)^(row&7) -> reads spread all 8
// bank groups with 8-lane broadcasts (conflict-free); staged via linear-dest
// global_load_lds + inverse-swizzled SOURCE address. i/jj strides (16384B)
// fold into ds-offset immediates; only 2 XORs of per-quad address VALU.
// K fully inside the block: single LDS combine, no workspace, no 2nd kernel.
__global__ __launch_bounds__(512, 2) void mam_fused9(
    const float* __restrict__ x, const float* __restrict__ w,
    const float* __restrict__ bias, float* __restrict__ out)
{
    __shared__ __align__(16) float sm[32768];   // 128 KB: x[32][512] | w[32][512]

    float* xs  = sm;            // 64 KB
    float* wsh = sm + 16384;    // 64 KB

    const int t    = threadIdx.x;
    const int lane = t & 63;
    const int kq   = __builtin_amdgcn_readfirstlane(t >> 6);   // k-chunk 0..7

    // XCD-chunked bijective swizzle (512 = 8 * 64): chunk of 64 wg = 8 n-blocks
    // x 8 j-blocks -> ~1 MB x + 0.5 MB w per XCD L2.
    const int wg0 = (int)blockIdx.x;
    const int wg  = (wg0 & 7) * 64 + (wg0 >> 3);
    const int bx  = wg & 7;             // j-block (32 cols)
    const int by  = wg >> 3;            // n-block (32 rows), 0..63
    const int n0  = by * 32;
    const int j0  = bx * 32;

    const int rn = lane >> 3;           // 0..7
    const int cj = lane & 7;            // 0..7

    // ---- Stage both tiles, swizzled. Wave kq stages rows 4kq..4kq+3 of each.
    // Element [row][k] lives at LDS slot (k>>2)^(row&7): dest linear + lane*16,
    // source slot = dest slot ^ (row&7) (per-lane global addr; rule #21).
#pragma unroll
    for (int p = 0; p < 4; ++p) {
        const int row = kq * 4 + p;
        const int so  = (lane ^ (row & 7)) << 2;   // source float offset (16B slot)
#pragma unroll
        for (int h = 0; h < 2; ++h) {
            __builtin_amdgcn_global_load_lds(
                (glb_f*)(x + (size_t)(n0 + row) * K_ + h * 256 + so),
                (lds_f*)(xs + row * 512 + h * 256), 16, 0, 0);
            __builtin_amdgcn_global_load_lds(
                (glb_f*)(w + (size_t)(j0 + row) * K_ + h * 256 + so),
                (lds_f*)(wsh + row * 512 + h * 256), 16, 0, 0);
        }
    }

    float mx[4][4], mn[4][4];
#pragma unroll
    for (int i = 0; i < 4; ++i)
#pragma unroll
        for (int jj = 0; jj < 4; ++jj) {
            mx[i][jj] = -__builtin_inff();
            mn[i][jj] =  __builtin_inff();
        }

    __syncthreads();   // vmcnt(0) drain: tiles resident

    const int xb = rn * 512 + kq * 64;   // float base of lane's x row 0, k-chunk
    const int wb = cj * 512 + kq * 64;

    // 16 quads of 4 k: 8 broadcast ds_read_b128 + 128 VALU each.
#pragma unroll
    for (int q = 0; q < 16; ++q) {
        const int xo = xb + ((q ^ rn) << 2);   // swizzled slot, same for all i
        const int wo = wb + ((q ^ cj) << 2);
        f32x4 xv[4], wv[4];
#pragma unroll
        for (int i = 0; i < 4; ++i)
            xv[i] = *(const f32x4*)&xs[xo + i * 4096];     // +i*16384B: ds imm
#pragma unroll
        for (int jj = 0; jj < 4; ++jj)
            wv[jj] = *(const f32x4*)&wsh[wo + jj * 4096];
#pragma unroll
        for (int i = 0; i < 4; ++i)
#pragma unroll
            for (int jj = 0; jj < 4; ++jj) {
                const f32x4 a = xv[i], b = wv[jj];
                const float p0 = a.x * b.x, p1 = a.y * b.y;
                const float p2 = a.z * b.z, p3 = a.w * b.w;
                MAX3(mx[i][jj], p0, p1); MAX3(mx[i][jj], p2, p3);
                MIN3(mn[i][jj], p0, p1); MIN3(mn[i][jj], p2, p3);
            }
    }

    __syncthreads();   // all tile reads done; safe to alias with partials

    // Combine the 8 k-chunks: partials in float2 cb[8][32][36] (73,728 B,
    // aliases the dead tiles; pitch 36 -> <=4-way on b64, near-free).
    float2* cb = (float2*)sm;
#pragma unroll
    for (int i = 0; i < 4; ++i)
#pragma unroll
        for (int jj = 0; jj < 4; ++jj) {
            const int r = rn + 8 * i, c = cj + 8 * jj;
            float2 v; v.x = mx[i][jj]; v.y = mn[i][jj];
            cb[(kq * 32 + r) * 36 + c] = v;
        }
    __syncthreads();

    // 1024 outputs, 512 threads x 2: 8-way merge + bias, coalesced store.
#pragma unroll
    for (int e = 0; e < 2; ++e) {
        const int o = t + e * 512;
        const int r = o >> 5, c = o & 31;
        float a = -__builtin_inff(), b = __builtin_inff();
#pragma unroll
        for (int kk = 0; kk < 8; ++kk) {
            const float2 v = cb[(kk * 32 + r) * 36 + c];
            a = fmaxf(a, v.x);
            b = fminf(b, v.y);
        }
        out[(size_t)(n0 + r) * J_ + j0 + c] = a + b + bias[j0 + c];
    }
}

extern "C" void kernel_launch(void* const* d_in, const int* in_sizes, int n_in,
                              void* d_out, int out_size, void* d_ws, size_t ws_size,
                              hipStream_t stream) {
    const float* x    = (const float*)d_in[0];
    const float* w    = (const float*)d_in[1];
    const float* bias = (const float*)d_in[2];
    float* out = (float*)d_out;

    dim3 grid(512);   // 64 n-blocks x 8 j-blocks, XCD-swizzled in-kernel
    mam_fused9<<<grid, 512, 0, stream>>>(x, w, bias, out);
}